// Round 1
// baseline (310.554 us; speedup 1.0000x reference)
//
#include <hip/hip_runtime.h>
#include <cmath>

// ---------------------------------------------------------------------------
// NaiveAttention on MI355X (gfx950)
//   x[2,2048,1024] f32, W_qkv[3072,1024] f32, W_out[1024,1024] f32 -> out f32
// Pipeline: cast->bf16; GEMM1 (qkv) scatter to Q(scaled)/K/[V transposed];
//           MFMA flash attention; GEMM2 -> f32 out.
// MFMA 16x16x32 bf16 layouts (verified per guide):
//   C/D: col = lane&15, row = (lane>>4)*4 + reg
//   A  : m = lane&15,  k = (lane>>4)*8 + j   (8 contiguous bf16 per lane)
//   B  : n = lane&15,  k = (lane>>4)*8 + j   (mirrored)
// ---------------------------------------------------------------------------

typedef unsigned short u16;
typedef short short8 __attribute__((ext_vector_type(8)));
typedef float floatx4 __attribute__((ext_vector_type(4)));

#define B_SZ 2
#define T_SZ 2048
#define D_SZ 1024
#define H_SZ 16
#define HD_SZ 64
#define M_SZ (B_SZ * T_SZ)      // 4096
#define LOG2E 1.44269504088896f

__device__ __forceinline__ u16 f2bf(float f) {
  unsigned u = __float_as_uint(f);
  u += 0x7fffu + ((u >> 16) & 1u);   // RNE
  return (u16)(u >> 16);
}

// ---------------- cast fp32 -> bf16, vectorized ----------------
__global__ __launch_bounds__(256) void cast_bf16(const float* __restrict__ in,
                                                 u16* __restrict__ out, int n4) {
  int i = blockIdx.x * 256 + threadIdx.x;
  if (i < n4) {
    float4 f = ((const float4*)in)[i];
    ushort4 o;
    o.x = f2bf(f.x); o.y = f2bf(f.y); o.z = f2bf(f.z); o.w = f2bf(f.w);
    ((ushort4*)out)[i] = o;
  }
}

// ---------------- 128x128 bf16 MFMA GEMM: C = A * Bt^T ----------------
// A[Mdim][Kdim], Bt[Ndim][Kdim] row-major bf16.  Kdim % 32 == 0.
// EPI 0: qkv scatter -> Qg (x0.125), Kg ([bh][t][d]), Vtg ([bh][d][t])
// EPI 1: Cout[m*1024+n] = fp32
template <int EPI>
__global__ __launch_bounds__(256) void gemm128(const u16* __restrict__ A,
                                               const u16* __restrict__ Bt,
                                               float* __restrict__ Cout,
                                               u16* __restrict__ Qg,
                                               u16* __restrict__ Kg,
                                               u16* __restrict__ Vtg,
                                               int Kdim) {
  __shared__ u16 As[128 * 40];   // stride 40 (=80B, 16B-aligned, bank-friendly)
  __shared__ u16 Bs[128 * 40];
  const int tid = threadIdx.x;
  const int lane = tid & 63;
  const int wave = tid >> 6;
  const int quad = lane >> 4;
  const int l16 = lane & 15;
  const int wm = wave >> 1, wn = wave & 1;
  const int m0 = blockIdx.y * 128;
  const int n0 = blockIdx.x * 128;

  floatx4 acc[4][4];
#pragma unroll
  for (int i = 0; i < 4; i++)
#pragma unroll
    for (int j = 0; j < 4; j++) acc[i][j] = (floatx4){0.f, 0.f, 0.f, 0.f};

  const int r0 = tid >> 2;  // staging row 0..63 (and +64)
  const int s0 = tid & 3;   // 16B segment within 32-col tile

  for (int k0 = 0; k0 < Kdim; k0 += 32) {
    const uint4 a0v = *(const uint4*)(A + (size_t)(m0 + r0) * Kdim + k0 + s0 * 8);
    const uint4 a1v = *(const uint4*)(A + (size_t)(m0 + 64 + r0) * Kdim + k0 + s0 * 8);
    const uint4 b0v = *(const uint4*)(Bt + (size_t)(n0 + r0) * Kdim + k0 + s0 * 8);
    const uint4 b1v = *(const uint4*)(Bt + (size_t)(n0 + 64 + r0) * Kdim + k0 + s0 * 8);
    __syncthreads();  // previous iter's frag reads done
    *(uint4*)&As[r0 * 40 + s0 * 8] = a0v;
    *(uint4*)&As[(64 + r0) * 40 + s0 * 8] = a1v;
    *(uint4*)&Bs[r0 * 40 + s0 * 8] = b0v;
    *(uint4*)&Bs[(64 + r0) * 40 + s0 * 8] = b1v;
    __syncthreads();
    short8 af[4], bf[4];
#pragma unroll
    for (int mt = 0; mt < 4; mt++)
      af[mt] = *(const short8*)&As[(wm * 64 + mt * 16 + l16) * 40 + quad * 8];
#pragma unroll
    for (int nt = 0; nt < 4; nt++)
      bf[nt] = *(const short8*)&Bs[(wn * 64 + nt * 16 + l16) * 40 + quad * 8];
#pragma unroll
    for (int mt = 0; mt < 4; mt++)
#pragma unroll
      for (int nt = 0; nt < 4; nt++)
        acc[mt][nt] = __builtin_amdgcn_mfma_f32_16x16x32_bf16(af[mt], bf[nt], acc[mt][nt], 0, 0, 0);
  }

#pragma unroll
  for (int mt = 0; mt < 4; mt++) {
#pragma unroll
    for (int nt = 0; nt < 4; nt++) {
#pragma unroll
      for (int r = 0; r < 4; r++) {
        const int m = m0 + wm * 64 + mt * 16 + quad * 4 + r;
        const int n = n0 + wn * 64 + nt * 16 + l16;
        float v = acc[mt][nt][r];
        if (EPI == 1) {
          Cout[(size_t)m * 1024 + n] = v;
        } else {
          const int b = m >> 11, t = m & 2047;
          const int which = n >> 10, rem = n & 1023;
          const int h = rem >> 6, d = rem & 63;
          const size_t bh = (size_t)(b * 16 + h);
          if (which == 0)
            Qg[((bh * 2048 + t) << 6) + d] = f2bf(v * 0.125f);  // fold hd^-0.5
          else if (which == 1)
            Kg[((bh * 2048 + t) << 6) + d] = f2bf(v);
          else
            Vtg[((bh * 64 + d) << 11) + t] = f2bf(v);           // V transposed
        }
      }
    }
  }
}

// ---------------- flash attention (causal, online softmax) ----------------
// grid: x = q-tile (T/64 = 32), y = b*H + h (32). block = 256 (4 waves).
// Wave w owns q-rows [qt*64 + w*16, +16).  K-tiles of 64 iterated 0..qt.
__global__ __launch_bounds__(256) void flash_attn(const u16* __restrict__ Qg,
                                                  const u16* __restrict__ Kg,
                                                  const u16* __restrict__ Vtg,
                                                  u16* __restrict__ Og) {
  __shared__ u16 Ks[64 * 72];       // K-tile  [kcol][d], stride 72
  __shared__ u16 Vs[64 * 72];       // V-tile transposed [d][kcol]
  __shared__ u16 Ps[4][16 * 72];    // per-wave P [row][kcol]
  const int tid = threadIdx.x;
  const int lane = tid & 63, wave = tid >> 6;
  const int quad = lane >> 4, l16 = lane & 15;
  const int qt = blockIdx.x, bh = blockIdx.y;
  const size_t base = (size_t)bh * T_SZ * HD_SZ;   // Q/K element base
  const size_t vbase = (size_t)bh * HD_SZ * T_SZ;  // Vt element base

  // Q fragments for this wave's 16 rows (kept in regs all kernel)
  const int qrow = qt * 64 + wave * 16 + l16;
  short8 qf0 = *(const short8*)(Qg + base + (size_t)qrow * 64 + quad * 8);
  short8 qf1 = *(const short8*)(Qg + base + (size_t)qrow * 64 + 32 + quad * 8);

  float m_i[4], l_i[4];
  floatx4 o_acc[4];
#pragma unroll
  for (int r = 0; r < 4; r++) { m_i[r] = -INFINITY; l_i[r] = 0.f; }
#pragma unroll
  for (int dt = 0; dt < 4; dt++) o_acc[dt] = (floatx4){0.f, 0.f, 0.f, 0.f};

  const int r0 = tid >> 2;  // staging row 0..63
  const int s0 = tid & 3;   // segments s0 and s0+4 (8 x 16B per 128B row)

  for (int kt = 0; kt <= qt; kt++) {
    const int kbase = kt * 64;
    const uint4 kv0 = *(const uint4*)(Kg + base + (size_t)(kbase + r0) * 64 + s0 * 8);
    const uint4 kv1 = *(const uint4*)(Kg + base + (size_t)(kbase + r0) * 64 + (s0 + 4) * 8);
    const uint4 vv0 = *(const uint4*)(Vtg + vbase + (size_t)r0 * 2048 + kbase + s0 * 8);
    const uint4 vv1 = *(const uint4*)(Vtg + vbase + (size_t)r0 * 2048 + kbase + (s0 + 4) * 8);
    __syncthreads();  // previous iter's LDS reads done
    *(uint4*)&Ks[r0 * 72 + s0 * 8] = kv0;
    *(uint4*)&Ks[r0 * 72 + (s0 + 4) * 8] = kv1;
    *(uint4*)&Vs[r0 * 72 + s0 * 8] = vv0;
    *(uint4*)&Vs[r0 * 72 + (s0 + 4) * 8] = vv1;
    __syncthreads();

    // S = Q K^T  (scale pre-folded into Q)
    floatx4 s_acc[4];
#pragma unroll
    for (int nt = 0; nt < 4; nt++) {
      short8 b0 = *(const short8*)&Ks[(nt * 16 + l16) * 72 + quad * 8];
      short8 b1 = *(const short8*)&Ks[(nt * 16 + l16) * 72 + 32 + quad * 8];
      floatx4 s = (floatx4){0.f, 0.f, 0.f, 0.f};
      s = __builtin_amdgcn_mfma_f32_16x16x32_bf16(qf0, b0, s, 0, 0, 0);
      s = __builtin_amdgcn_mfma_f32_16x16x32_bf16(qf1, b1, s, 0, 0, 0);
      s_acc[nt] = s;
    }

    if (kt == qt) {  // diagonal tile: causal mask
#pragma unroll
      for (int nt = 0; nt < 4; nt++) {
        const int kc = nt * 16 + l16;
#pragma unroll
        for (int r = 0; r < 4; r++) {
          const int qr = wave * 16 + quad * 4 + r;
          if (kc > qr) s_acc[nt][r] = -INFINITY;
        }
      }
    }

    // online softmax: rows live across the 16 lanes of this quad
    float mnew[4], alpha[4];
#pragma unroll
    for (int r = 0; r < 4; r++) {
      float mx = fmaxf(fmaxf(s_acc[0][r], s_acc[1][r]), fmaxf(s_acc[2][r], s_acc[3][r]));
#pragma unroll
      for (int off = 1; off < 16; off <<= 1) mx = fmaxf(mx, __shfl_xor(mx, off, 64));
      mnew[r] = fmaxf(m_i[r], mx);
      alpha[r] = exp2f((m_i[r] - mnew[r]) * LOG2E);
      m_i[r] = mnew[r];
    }

    float rowsum[4] = {0.f, 0.f, 0.f, 0.f};
    u16 pbits[4][4];
#pragma unroll
    for (int nt = 0; nt < 4; nt++) {
#pragma unroll
      for (int r = 0; r < 4; r++) {
        float p = exp2f((s_acc[nt][r] - mnew[r]) * LOG2E);
        rowsum[r] += p;
        pbits[nt][r] = f2bf(p);
      }
    }
#pragma unroll
    for (int r = 0; r < 4; r++) {
      float rs = rowsum[r];
#pragma unroll
      for (int off = 1; off < 16; off <<= 1) rs += __shfl_xor(rs, off, 64);
      l_i[r] = l_i[r] * alpha[r] + rs;
    }
#pragma unroll
    for (int dt = 0; dt < 4; dt++)
#pragma unroll
      for (int r = 0; r < 4; r++) o_acc[dt][r] *= alpha[r];

    // P: C-layout -> LDS -> A-layout (simplest correct transform)
#pragma unroll
    for (int nt = 0; nt < 4; nt++)
#pragma unroll
      for (int r = 0; r < 4; r++)
        Ps[wave][(quad * 4 + r) * 72 + nt * 16 + l16] = pbits[nt][r];
    __syncthreads();

    short8 pf0 = *(const short8*)&Ps[wave][l16 * 72 + quad * 8];
    short8 pf1 = *(const short8*)&Ps[wave][l16 * 72 + 32 + quad * 8];
#pragma unroll
    for (int dt = 0; dt < 4; dt++) {
      short8 v0 = *(const short8*)&Vs[(dt * 16 + l16) * 72 + quad * 8];
      short8 v1 = *(const short8*)&Vs[(dt * 16 + l16) * 72 + 32 + quad * 8];
      o_acc[dt] = __builtin_amdgcn_mfma_f32_16x16x32_bf16(pf0, v0, o_acc[dt], 0, 0, 0);
      o_acc[dt] = __builtin_amdgcn_mfma_f32_16x16x32_bf16(pf1, v1, o_acc[dt], 0, 0, 0);
    }
  }

  // epilogue: O / l -> attn_out [b][t][h*64+d] bf16
  const int b = bh >> 4, h = bh & 15;
#pragma unroll
  for (int dt = 0; dt < 4; dt++) {
#pragma unroll
    for (int r = 0; r < 4; r++) {
      const int t = qt * 64 + wave * 16 + quad * 4 + r;
      const int col = h * 64 + dt * 16 + l16;
      Og[((size_t)(b * 2048 + t) << 10) + col] = f2bf(o_acc[dt][r] / l_i[r]);
    }
  }
}

// ---------------------------------------------------------------------------
extern "C" void kernel_launch(void* const* d_in, const int* in_sizes, int n_in,
                              void* d_out, int out_size, void* d_ws, size_t ws_size,
                              hipStream_t stream) {
  const float* x = (const float*)d_in[0];      // [2,2048,1024]
  const float* Wqkv = (const float*)d_in[1];   // [3072,1024]
  const float* Wout = (const float*)d_in[2];   // [1024,1024]
  float* out = (float*)d_out;                  // [2,2048,1024] f32

  char* ws = (char*)d_ws;
  u16* xb    = (u16*)(ws + 0);          //  8,388,608 B  [4096][1024]
  u16* wqkvb = (u16*)(ws + 8388608);    //  6,291,456 B  [3072][1024]
  u16* woutb = (u16*)(ws + 14680064);   //  2,097,152 B  [1024][1024]
  u16* Qg    = (u16*)(ws + 16777216);   //  8,388,608 B  [32][2048][64] (x0.125)
  u16* Kg    = (u16*)(ws + 25165824);   //  8,388,608 B  [32][2048][64]
  u16* Vtg   = (u16*)(ws + 33554432);   //  8,388,608 B  [32][64][2048]
  u16* attn  = (u16*)(ws + 41943040);   //  8,388,608 B  [4096][1024]
  // total ws use: 50,331,648 B

  cast_bf16<<<4096, 256, 0, stream>>>(x, xb, 1048576);
  cast_bf16<<<3072, 256, 0, stream>>>(Wqkv, wqkvb, 786432);
  cast_bf16<<<1024, 256, 0, stream>>>(Wout, woutb, 262144);

  // qkv = x @ Wqkv^T, scatter to Q/K/Vt
  gemm128<0><<<dim3(24, 32), 256, 0, stream>>>(xb, wqkvb, nullptr, Qg, Kg, Vtg, 1024);

  // causal flash attention
  flash_attn<<<dim3(32, 32), 256, 0, stream>>>(Qg, Kg, Vtg, attn);

  // out = attn @ Wout^T
  gemm128<1><<<dim3(8, 32), 256, 0, stream>>>(attn, woutb, out, nullptr, nullptr, nullptr, 1024);
}

// Round 2
// 300.910 us; speedup vs baseline: 1.0320x; 1.0320x over previous
//
#include <hip/hip_runtime.h>
#include <cmath>

// ---------------------------------------------------------------------------
// NaiveAttention on MI355X (gfx950)
//   x[2,2048,1024] f32, W_qkv[3072,1024] f32, W_out[1024,1024] f32 -> out f32
// Pipeline: cast->bf16; GEMM1 (qkv) scatter to Q(scaled)/K/[V transposed];
//           barrier-free transposed MFMA flash attention; GEMM2 -> f32 out.
// MFMA 16x16x32 bf16 layouts (verified per guide):
//   C/D: col = lane&15, row = (lane>>4)*4 + reg
//   A  : m = lane&15,  k = (lane>>4)*8 + j   (8 contiguous bf16 per lane)
//   B  : n = lane&15,  k = (lane>>4)*8 + j   (identical mapping)
// Flash trick: compute S^T = K*Q^T and O^T = V^T*P^T so softmax rows map to
// lane index l16 -> per-lane scalar m/l/alpha, 2 shuffles per reduction,
// no __syncthreads anywhere (K/V frags direct from global, P via per-wave LDS).
// ---------------------------------------------------------------------------

typedef unsigned short u16;
typedef unsigned int u32;
typedef short short8 __attribute__((ext_vector_type(8)));
typedef float floatx4 __attribute__((ext_vector_type(4)));

#define B_SZ 2
#define T_SZ 2048
#define D_SZ 1024
#define H_SZ 16
#define HD_SZ 64
#define LOG2E 1.44269504088896f

__device__ __forceinline__ u16 f2bf(float f) {
  unsigned u = __float_as_uint(f);
  u += 0x7fffu + ((u >> 16) & 1u);   // RNE
  return (u16)(u >> 16);
}

// pack two f32 -> two bf16 (truncation) in one v_perm
__device__ __forceinline__ u32 pack_bf2(float lo, float hi) {
  return __builtin_amdgcn_perm(__float_as_uint(hi), __float_as_uint(lo), 0x07060302u);
}

// ---------------- cast fp32 -> bf16, vectorized ----------------
__global__ __launch_bounds__(256) void cast_bf16(const float* __restrict__ in,
                                                 u16* __restrict__ out, int n4) {
  int i = blockIdx.x * 256 + threadIdx.x;
  if (i < n4) {
    float4 f = ((const float4*)in)[i];
    ushort4 o;
    o.x = f2bf(f.x); o.y = f2bf(f.y); o.z = f2bf(f.z); o.w = f2bf(f.w);
    ((ushort4*)out)[i] = o;
  }
}

// ---------------- 128x128 bf16 MFMA GEMM: C = A * Bt^T ----------------
template <int EPI>
__global__ __launch_bounds__(256) void gemm128(const u16* __restrict__ A,
                                               const u16* __restrict__ Bt,
                                               float* __restrict__ Cout,
                                               u16* __restrict__ Qg,
                                               u16* __restrict__ Kg,
                                               u16* __restrict__ Vtg,
                                               int Kdim) {
  __shared__ u16 As[128 * 40];
  __shared__ u16 Bs[128 * 40];
  const int tid = threadIdx.x;
  const int lane = tid & 63;
  const int wave = tid >> 6;
  const int quad = lane >> 4;
  const int l16 = lane & 15;
  const int wm = wave >> 1, wn = wave & 1;
  const int m0 = blockIdx.y * 128;
  const int n0 = blockIdx.x * 128;

  floatx4 acc[4][4];
#pragma unroll
  for (int i = 0; i < 4; i++)
#pragma unroll
    for (int j = 0; j < 4; j++) acc[i][j] = (floatx4){0.f, 0.f, 0.f, 0.f};

  const int r0 = tid >> 2;
  const int s0 = tid & 3;

  for (int k0 = 0; k0 < Kdim; k0 += 32) {
    const uint4 a0v = *(const uint4*)(A + (size_t)(m0 + r0) * Kdim + k0 + s0 * 8);
    const uint4 a1v = *(const uint4*)(A + (size_t)(m0 + 64 + r0) * Kdim + k0 + s0 * 8);
    const uint4 b0v = *(const uint4*)(Bt + (size_t)(n0 + r0) * Kdim + k0 + s0 * 8);
    const uint4 b1v = *(const uint4*)(Bt + (size_t)(n0 + 64 + r0) * Kdim + k0 + s0 * 8);
    __syncthreads();
    *(uint4*)&As[r0 * 40 + s0 * 8] = a0v;
    *(uint4*)&As[(64 + r0) * 40 + s0 * 8] = a1v;
    *(uint4*)&Bs[r0 * 40 + s0 * 8] = b0v;
    *(uint4*)&Bs[(64 + r0) * 40 + s0 * 8] = b1v;
    __syncthreads();
    short8 af[4], bf[4];
#pragma unroll
    for (int mt = 0; mt < 4; mt++)
      af[mt] = *(const short8*)&As[(wm * 64 + mt * 16 + l16) * 40 + quad * 8];
#pragma unroll
    for (int nt = 0; nt < 4; nt++)
      bf[nt] = *(const short8*)&Bs[(wn * 64 + nt * 16 + l16) * 40 + quad * 8];
#pragma unroll
    for (int mt = 0; mt < 4; mt++)
#pragma unroll
      for (int nt = 0; nt < 4; nt++)
        acc[mt][nt] = __builtin_amdgcn_mfma_f32_16x16x32_bf16(af[mt], bf[nt], acc[mt][nt], 0, 0, 0);
  }

#pragma unroll
  for (int mt = 0; mt < 4; mt++) {
#pragma unroll
    for (int nt = 0; nt < 4; nt++) {
#pragma unroll
      for (int r = 0; r < 4; r++) {
        const int m = m0 + wm * 64 + mt * 16 + quad * 4 + r;
        const int n = n0 + wn * 64 + nt * 16 + l16;
        float v = acc[mt][nt][r];
        if (EPI == 1) {
          Cout[(size_t)m * 1024 + n] = v;
        } else {
          const int b = m >> 11, t = m & 2047;
          const int which = n >> 10, rem = n & 1023;
          const int h = rem >> 6, d = rem & 63;
          const size_t bh = (size_t)(b * 16 + h);
          if (which == 0)
            Qg[((bh * 2048 + t) << 6) + d] = f2bf(v * 0.125f);
          else if (which == 1)
            Kg[((bh * 2048 + t) << 6) + d] = f2bf(v);
          else
            Vtg[((bh * 64 + d) << 11) + t] = f2bf(v);
        }
      }
    }
  }
}

// ---------------- barrier-free transposed flash attention ----------------
// grid (32, 32): y = bh, g = (x + y) % 32 selects the 64-row q-tile.
// block = 256 = 4 waves; wave w owns q-rows [g*64 + w*16, +16).
// All 4 waves iterate kt = 0..g (identical trip count -> lockstep, L1 sharing).
__global__ __launch_bounds__(256) void flash_attn(const u16* __restrict__ Qg,
                                                  const u16* __restrict__ Kg,
                                                  const u16* __restrict__ Vtg,
                                                  u16* __restrict__ Og) {
  __shared__ u16 Ps[4][16 * 72];   // per-wave P buffer [qrow=l16][kcol], stride 72
  const int tid = threadIdx.x;
  const int lane = tid & 63, wave = tid >> 6;
  const int quad = lane >> 4, l16 = lane & 15;
  const int bh = blockIdx.y;
  const int g = (blockIdx.x + blockIdx.y) & 31;   // q-tile swizzle for balance
  const size_t base = (size_t)bh * T_SZ * HD_SZ;
  const size_t vbase = (size_t)bh * HD_SZ * T_SZ;

  const int t0 = g * 64 + wave * 16;   // this wave's first q-row

  // Q fragments (B-operand): lane holds Q[t0+l16][quad*8+j] (+32 for qf1)
  const short8 qf0 = *(const short8*)(Qg + base + (size_t)(t0 + l16) * 64 + quad * 8);
  const short8 qf1 = *(const short8*)(Qg + base + (size_t)(t0 + l16) * 64 + 32 + quad * 8);

  float m_i = -INFINITY, l_i = 0.f;
  floatx4 o_acc[4];   // O^T: row = d (dt*16+quad*4+reg), col = qrow = l16
#pragma unroll
  for (int dt = 0; dt < 4; dt++) o_acc[dt] = (floatx4){0.f, 0.f, 0.f, 0.f};

  u16* ps = &Ps[wave][0];

  for (int kt = 0; kt <= g; kt++) {
    const int kbase = kt * 64;
    const bool diag = (kt == g);

    // S^T = K * Q^T : s_acc[nt] rows = kcol (nt*16+quad*4+reg), col = qrow (l16)
    floatx4 s_acc[4];
#pragma unroll
    for (int nt = 0; nt < 4; nt++) {
      if (diag && nt > wave) {   // sub-tile fully above the diagonal
        s_acc[nt] = (floatx4){-INFINITY, -INFINITY, -INFINITY, -INFINITY};
        continue;
      }
      const u16* krow = Kg + base + (size_t)(kbase + nt * 16 + l16) * 64;
      short8 a0 = *(const short8*)(krow + quad * 8);
      short8 a1 = *(const short8*)(krow + 32 + quad * 8);
      floatx4 s = (floatx4){0.f, 0.f, 0.f, 0.f};
      s = __builtin_amdgcn_mfma_f32_16x16x32_bf16(a0, qf0, s, 0, 0, 0);
      s = __builtin_amdgcn_mfma_f32_16x16x32_bf16(a1, qf1, s, 0, 0, 0);
      if (diag && nt == wave) {  // partial mask on the diagonal sub-tile
#pragma unroll
        for (int r = 0; r < 4; r++)
          if (quad * 4 + r > l16) s[r] = -INFINITY;
      }
      s_acc[nt] = s;
    }

    // per-lane online softmax (row = l16, spread across 4 quads)
    float mx = -INFINITY;
#pragma unroll
    for (int nt = 0; nt < 4; nt++)
#pragma unroll
      for (int r = 0; r < 4; r++) mx = fmaxf(mx, s_acc[nt][r]);
    mx = fmaxf(mx, __shfl_xor(mx, 16, 64));
    mx = fmaxf(mx, __shfl_xor(mx, 32, 64));
    const float mnew = fmaxf(m_i, mx);
    const float alpha = exp2f((m_i - mnew) * LOG2E);
    m_i = mnew;

    float rs = 0.f;
#pragma unroll
    for (int nt = 0; nt < 4; nt++) {
      float p0 = exp2f((s_acc[nt][0] - mnew) * LOG2E);
      float p1 = exp2f((s_acc[nt][1] - mnew) * LOG2E);
      float p2 = exp2f((s_acc[nt][2] - mnew) * LOG2E);
      float p3 = exp2f((s_acc[nt][3] - mnew) * LOG2E);
      rs += (p0 + p1) + (p2 + p3);
      uint2 w;
      w.x = pack_bf2(p0, p1);
      w.y = pack_bf2(p2, p3);
      *(uint2*)&ps[l16 * 72 + nt * 16 + quad * 4] = w;   // P[l16][kcol]
    }
    rs += __shfl_xor(rs, 16, 64);
    rs += __shfl_xor(rs, 32, 64);
    l_i = l_i * alpha + rs;

#pragma unroll
    for (int dt = 0; dt < 4; dt++)
#pragma unroll
      for (int r = 0; r < 4; r++) o_acc[dt][r] *= alpha;

    // P back in A/B layout (wave-private LDS, no barrier needed)
    const short8 pf0 = *(const short8*)&ps[l16 * 72 + quad * 8];
    const short8 pf1 = *(const short8*)&ps[l16 * 72 + 32 + quad * 8];

    const bool skip_hi = diag && (wave < 2);   // kcols 32..63 all masked
#pragma unroll
    for (int dt = 0; dt < 4; dt++) {
      const u16* vrow = Vtg + vbase + (size_t)(dt * 16 + l16) * 2048 + kbase;
      short8 v0 = *(const short8*)(vrow + quad * 8);
      o_acc[dt] = __builtin_amdgcn_mfma_f32_16x16x32_bf16(v0, pf0, o_acc[dt], 0, 0, 0);
      if (!skip_hi) {
        short8 v1 = *(const short8*)(vrow + 32 + quad * 8);
        o_acc[dt] = __builtin_amdgcn_mfma_f32_16x16x32_bf16(v1, pf1, o_acc[dt], 0, 0, 0);
      }
    }
  }

  // epilogue: O^T/l -> attn [b][t][h*64+d] bf16 (paired u32 stores)
  const int b = bh >> 4, h = bh & 15;
  const float inv_l = 1.0f / l_i;
  const size_t row = ((size_t)(b * 2048 + t0 + l16) << 10) + h * 64;
#pragma unroll
  for (int dt = 0; dt < 4; dt++) {
    float o0 = o_acc[dt][0] * inv_l, o1 = o_acc[dt][1] * inv_l;
    float o2 = o_acc[dt][2] * inv_l, o3 = o_acc[dt][3] * inv_l;
    *(u32*)&Og[row + dt * 16 + quad * 4] = pack_bf2(o0, o1);
    *(u32*)&Og[row + dt * 16 + quad * 4 + 2] = pack_bf2(o2, o3);
  }
}

// ---------------------------------------------------------------------------
extern "C" void kernel_launch(void* const* d_in, const int* in_sizes, int n_in,
                              void* d_out, int out_size, void* d_ws, size_t ws_size,
                              hipStream_t stream) {
  const float* x = (const float*)d_in[0];
  const float* Wqkv = (const float*)d_in[1];
  const float* Wout = (const float*)d_in[2];
  float* out = (float*)d_out;

  char* ws = (char*)d_ws;
  u16* xb    = (u16*)(ws + 0);
  u16* wqkvb = (u16*)(ws + 8388608);
  u16* woutb = (u16*)(ws + 14680064);
  u16* Qg    = (u16*)(ws + 16777216);
  u16* Kg    = (u16*)(ws + 25165824);
  u16* Vtg   = (u16*)(ws + 33554432);
  u16* attn  = (u16*)(ws + 41943040);

  cast_bf16<<<4096, 256, 0, stream>>>(x, xb, 1048576);
  cast_bf16<<<3072, 256, 0, stream>>>(Wqkv, wqkvb, 786432);
  cast_bf16<<<1024, 256, 0, stream>>>(Wout, woutb, 262144);

  gemm128<0><<<dim3(24, 32), 256, 0, stream>>>(xb, wqkvb, nullptr, Qg, Kg, Vtg, 1024);

  flash_attn<<<dim3(32, 32), 256, 0, stream>>>(Qg, Kg, Vtg, attn);

  gemm128<1><<<dim3(8, 32), 256, 0, stream>>>(attn, woutb, out, nullptr, nullptr, nullptr, 1024);
}